// Round 2
// baseline (374.817 us; speedup 1.0000x reference)
//
#include <hip/hip_runtime.h>

// MaskAttention: B=2,S=3144,C=256,H=8,HD=32, mask-softmax attention with vh=kh,
// LePE 5x5 depthwise conv on v[:,8:], output projection.
// I/O: ALL float32. Internal: bf16 MFMA, f32 accum.
//
// softmax(qk + log(m+eps)) == normalize((m+eps)*exp(qk)); |qk| is tiny, so fixed
// shift M=0 -> no online max; k-range partials additive => split-K.
//
// R2 changes vs 324us/R1:
//  - k_flash: explicit register double-buffer of kf/v0/v1 (tile t+1 loads issued
//    BEFORE the counted s_waitcnt vmcnt(16) fence -> memory clobber pins issue
//    order, loads stay in flight across the whole tile-t compute).
//  - mask LDS read via inline-asm ds_read_b128 + lgkmcnt(0): compiler cannot see
//    a dep on global_load_lds, so it cannot insert a vmcnt(0) drain.
//  - kws carries k*SCALE*log2e -> softmax uses v_exp_f32 (exp2) directly, no
//    per-element mul. vfrag/V keeps k*SCALE (vh=kh must stay unscaled).
//  - k_cvt prepass: x and wq/wk/wv converted to bf16 ONCE (xb in d_out upper
//    half, w3b in lepe region, dead until k_lepe). k_qkv loses all on-the-fly
//    f32->bf16 VALU and half its read bytes.

#define S_LEN 3144
#define SP    3200            // S padded to 64 (50 k-tiles; 0..48 fully valid)
#define HEADS 8
#define HD    32
#define BATCH 2
#define MROWS (BATCH*S_LEN)   // 6288
#define NPIX  3136            // 56*56
#define SCALE_F 0.17677669529663687f   // 32^-0.5
#define KQ_SC   0.25504472665352026f   // SCALE_F * log2(e)

typedef __bf16 bf16x8  __attribute__((ext_vector_type(8)));
typedef __bf16 bf16x4  __attribute__((ext_vector_type(4)));
typedef float  floatx4 __attribute__((ext_vector_type(4)));
typedef short  shortx4 __attribute__((ext_vector_type(4)));

static __device__ __forceinline__ float bf2f(unsigned int h) {
  union { unsigned int u; float f; } v; v.u = h << 16; return v.f;
}
static __device__ __forceinline__ unsigned short f2bf(float f) {
  union { __bf16 b; unsigned short u; } v; v.b = (__bf16)f; return v.u;
}
static __device__ __forceinline__ bf16x8 ldcvt8(const float* __restrict__ p) {
  float4 a = *(const float4*)p;
  float4 b = *(const float4*)(p + 4);
  bf16x8 r;
  r[0]=(__bf16)a.x; r[1]=(__bf16)a.y; r[2]=(__bf16)a.z; r[3]=(__bf16)a.w;
  r[4]=(__bf16)b.x; r[5]=(__bf16)b.y; r[6]=(__bf16)b.z; r[7]=(__bf16)b.w;
  return r;
}

#define GLOBAL_AS __attribute__((address_space(1)))
#define LDS_AS    __attribute__((address_space(3)))
static __device__ __forceinline__ void gload_lds16(const void* g, void* l) {
  __builtin_amdgcn_global_load_lds((const GLOBAL_AS void*)g, (LDS_AS void*)l, 16, 0, 0);
}

#define FENCE16() asm volatile("s_waitcnt vmcnt(16)" ::: "memory")
#define FENCE0()  asm volatile("s_waitcnt vmcnt(0)" ::: "memory")

// ---------------- K0: one-time f32 -> bf16 conversion (x, wq, wk, wv) ----------------
__global__ __launch_bounds__(256) void k_cvt(
    const float* __restrict__ x, const float* __restrict__ wq,
    const float* __restrict__ wk, const float* __restrict__ wv,
    unsigned short* __restrict__ xb, unsigned short* __restrict__ w3b)
{
  const int i = blockIdx.x * 256 + threadIdx.x;   // unit of 8 floats
  const int NX = MROWS * 32;                      // 201216
  const int NW = 8192;                            // 65536/8
  const float* src;
  unsigned short* dst;
  if (i < NX) { src = x + (size_t)i * 8; dst = xb + (size_t)i * 8; }
  else {
    const int j = i - NX;
    if (j >= 3 * NW) return;
    src = (j < NW) ? wq + (size_t)j * 8
        : (j < 2 * NW) ? wk + (size_t)(j - NW) * 8
                       : wv + (size_t)(j - 2 * NW) * 8;
    dst = w3b + (size_t)j * 8;
  }
  bf16x8 v = ldcvt8(src);
  *(bf16x8*)dst = v;
}

// ---------------- K1: fused q/k/v projection (bf16 in -> bf16 out) ----------------
// Grid (100, 12): blockIdx.x = bsel*50 + stile. Pad rows (s>=S_LEN) store 0.
__global__ __launch_bounds__(256) void k_qkv(
    const unsigned short* __restrict__ xb, const unsigned short* __restrict__ w3b,
    const float* __restrict__ bqp, const float* __restrict__ bkp,
    const float* __restrict__ bvp,
    unsigned short* __restrict__ qws, unsigned short* __restrict__ kws,
    unsigned short* __restrict__ vfrag, unsigned short* __restrict__ vstage)
{
  __shared__ unsigned short lds_t[64 * 65];   // transpose staging (k blocks only)
  const int lane = threadIdx.x & 63;
  const int wid  = threadIdx.x >> 6;
  const int c    = lane & 15, quad = lane >> 4;
  const int bsel  = blockIdx.x / 50;
  const int stile = blockIdx.x % 50;
  const int srow0 = stile * 64;
  const int ncol = blockIdx.y * 64;           // 0..767
  const int wsel = ncol >> 8;
  const int col0 = ncol & 255;

  const float* bptr = (wsel == 0) ? bqp : (wsel == 1) ? bkp : bvp;

  const int srow = srow0 + wid * 16 + c;
  const int arow = bsel * S_LEN + ((srow < S_LEN) ? srow : 0);  // clamp pad rows
  const unsigned short* ap = xb  + (size_t)arow * 256 + quad * 8;
  const unsigned short* bp = w3b + (size_t)(ncol + c) * 256 + quad * 8;

  floatx4 acc[4];
#pragma unroll
  for (int ct = 0; ct < 4; ++ct) acc[ct] = (floatx4){0.f, 0.f, 0.f, 0.f};

#pragma unroll
  for (int ks = 0; ks < 8; ++ks) {
    bf16x8 af = *(const bf16x8*)(ap + ks * 32);
#pragma unroll
    for (int ct = 0; ct < 4; ++ct) {
      bf16x8 bf = *(const bf16x8*)(bp + (size_t)ct * 16 * 256 + ks * 32);
      acc[ct] = __builtin_amdgcn_mfma_f32_16x16x32_bf16(af, bf, acc[ct], 0, 0, 0);
    }
  }

#pragma unroll
  for (int ct = 0; ct < 4; ++ct) {
    const int col = col0 + ct * 16 + c;
    const float bias = bptr[col];
#pragma unroll
    for (int r = 0; r < 4; ++r) {
      const int s = srow0 + wid * 16 + quad * 4 + r;   // 0..3199 within batch
      const int valid = (s < S_LEN);
      const float v = acc[ct][r] + bias;
      if (wsel == 0) {
        qws[(((size_t)(bsel * HEADS + (col >> 5))) * SP + s) * HD + (col & 31)] =
            valid ? f2bf(v) : (unsigned short)0;
      } else if (wsel == 1) {
        // QK-side copy carries log2e; V-side copy (lds_t->vfrag) does NOT.
        kws[(((size_t)(bsel * HEADS + (col >> 5))) * SP + s) * HD + (col & 31)] =
            valid ? f2bf(v * KQ_SC) : (unsigned short)0;
        lds_t[(ct * 16 + c) * 65 + (wid * 16 + quad * 4 + r)] =
            valid ? f2bf(v * SCALE_F) : (unsigned short)0;
      } else {
        if (valid) vstage[(size_t)(bsel * S_LEN + s) * 256 + col] = f2bf(v);
      }
    }
  }

  if (wsel == 1) {
    // vfrag: PV A-operand fragments in exact MFMA lane order.
    __syncthreads();
    const int tid = threadIdx.x;
#pragma unroll
    for (int j = 0; j < 4; ++j) {
      const int grp  = j * 4 + (tid >> 6);   // 0..15, wave-uniform
      const int l    = tid & 63;
      const int ct2  = grp & 3;
      const int half = (grp >> 2) & 1;
      const int hsel = grp >> 3;
      const int cc = l & 15, qq = l >> 4;
      const int cl = hsel * 32 + half * 16 + cc;
      const int rb = ct2 * 16 + qq * 4;
      union { shortx4 s4; unsigned short u[4]; } pk;
#pragma unroll
      for (int e = 0; e < 4; ++e) pk.u[e] = lds_t[cl * 65 + rb + e];
      const int hglob = (col0 >> 5) + hsel;
      const size_t off =
          ((((size_t)(bsel * HEADS + hglob) * 50 + stile) * 4 + ct2) * 2 + half) * 64 + l;
      *(shortx4*)(vfrag + off * 4) = pk.s4;
    }
  }
}

// ---------------- K2: LePE 5x5 depthwise conv on v[:,8:] ----------------
__global__ __launch_bounds__(256) void k_lepe(const unsigned short* __restrict__ vws,
                                              const float* __restrict__ cw,
                                              const float* __restrict__ cb,
                                              unsigned short* __restrict__ lepe)
{
  int idx = blockIdx.x * 256 + threadIdx.x;
  if (idx >= BATCH * NPIX * 32) return;
  const int cg = idx & 31;
  const int p  = (idx >> 5) % NPIX;
  const int b  = idx / (NPIX * 32);
  const int y  = p / 56, xx = p - y * 56;

  float acc[8];
  {
    float4 b0 = *(const float4*)(cb + cg * 8);
    float4 b1 = *(const float4*)(cb + cg * 8 + 4);
    acc[0]=b0.x; acc[1]=b0.y; acc[2]=b0.z; acc[3]=b0.w;
    acc[4]=b1.x; acc[5]=b1.y; acc[6]=b1.z; acc[7]=b1.w;
  }
#pragma unroll
  for (int dy = -2; dy <= 2; ++dy) {
    const int yy = y + dy;
    if ((unsigned)yy >= 56u) continue;
#pragma unroll
    for (int dx = -2; dx <= 2; ++dx) {
      const int xs = xx + dx;
      if ((unsigned)xs >= 56u) continue;
      uint4 vv = *(const uint4*)(vws + (size_t)(b * S_LEN + 8 + yy * 56 + xs) * 256 + cg * 8);
      const float* wp = cw + (size_t)((dy + 2) * 5 + (dx + 2)) * 256 + cg * 8;
      float4 w0 = *(const float4*)wp;
      float4 w1 = *(const float4*)(wp + 4);
      unsigned int va[4] = {vv.x, vv.y, vv.z, vv.w};
      acc[0] += bf2f(va[0] & 0xFFFFu) * w0.x;  acc[1] += bf2f(va[0] >> 16) * w0.y;
      acc[2] += bf2f(va[1] & 0xFFFFu) * w0.z;  acc[3] += bf2f(va[1] >> 16) * w0.w;
      acc[4] += bf2f(va[2] & 0xFFFFu) * w1.x;  acc[5] += bf2f(va[2] >> 16) * w1.y;
      acc[6] += bf2f(va[3] & 0xFFFFu) * w1.z;  acc[7] += bf2f(va[3] >> 16) * w1.w;
    }
  }
  unsigned int o[4];
#pragma unroll
  for (int j = 0; j < 4; ++j)
    o[j] = (unsigned int)f2bf(acc[2*j]) | ((unsigned int)f2bf(acc[2*j+1]) << 16);
  *((uint4*)(lepe + (size_t)(b * NPIX + p) * 256 + cg * 8)) = make_uint4(o[0], o[1], o[2], o[3]);
}

// ---------------- K3: flash attention, split-K + XCD-aware swizzle ----------------
// Register double-buffer (kf/v0/v1) + LDS mask double-buffer, one counted
// vmcnt(16) fence per tile. Mask LDS readback via inline-asm ds_read_b128
// (compiler cannot insert a vmcnt(0) drain for it).

static __device__ __forceinline__ void ldsm4(
    const unsigned (&ma)[4], floatx4& m0, floatx4& m1, floatx4& m2, floatx4& m3)
{
  asm volatile(
      "ds_read_b128 %0, %4\n\t"
      "ds_read_b128 %1, %5\n\t"
      "ds_read_b128 %2, %6\n\t"
      "ds_read_b128 %3, %7\n\t"
      "s_waitcnt lgkmcnt(0)"
      : "=v"(m0), "=v"(m1), "=v"(m2), "=v"(m3)
      : "v"(ma[0]), "v"(ma[1]), "v"(ma[2]), "v"(ma[3]));
}

static __device__ __forceinline__ void load_reg(
    const unsigned short* __restrict__ kb, const unsigned short* __restrict__ vb,
    int t, int c, int quad, int lane,
    bf16x8 (&kf)[4], shortx4 (&v0)[4], shortx4 (&v1)[4])
{
  const int k0 = t * 64;
  const unsigned short* tb = vb + (size_t)t * 2048;
#pragma unroll
  for (int ct = 0; ct < 4; ++ct) {
    kf[ct] = *(const bf16x8*)(kb + (size_t)(k0 + ct * 16 + c) * HD + quad * 8);
    v0[ct] = *(const shortx4*)(tb + (ct * 2 + 0) * 256 + lane * 4);
    v1[ct] = *(const shortx4*)(tb + (ct * 2 + 1) * 256 + lane * 4);
  }
}

static __device__ __forceinline__ void stage_mask(
    const float* const (&msrc)[4], const int (&goff4)[4], int k0, float* dst)
{
#pragma unroll
  for (int i = 0; i < 4; ++i)
    gload_lds16(msrc[i] + (k0 + goff4[i]), dst + i * 256);
}

static __device__ __forceinline__ void stage_mask_tail(
    const float* const (&msrc)[4], const int (&goff4)[4], int k0, float* dst)
{
#pragma unroll
  for (int i = 0; i < 4; ++i) {
    int kk = k0 + goff4[i];
    if (kk > S_LEN - 4) kk = S_LEN - 4;   // stay in-bounds; zeroed in softmax
    gload_lds16(msrc[i] + kk, dst + i * 256);
  }
}

template<bool TAIL>
static __device__ __forceinline__ void proc_reg(
    int k0, const bf16x8 (&kf)[4], const shortx4 (&v0)[4], const shortx4 (&v1)[4],
    const unsigned (&ma)[4], int quad, const bf16x8 qf,
    floatx4& o0, floatx4& o1, float& l_run)
{
  floatx4 s[4];
#pragma unroll
  for (int ct = 0; ct < 4; ++ct)
    s[ct] = __builtin_amdgcn_mfma_f32_16x16x32_bf16(kf[ct], qf,
               (floatx4){0.f,0.f,0.f,0.f}, 0, 0, 0);
  floatx4 mv0, mv1, mv2, mv3;
  ldsm4(ma, mv0, mv1, mv2, mv3);
  const floatx4 mv[4] = {mv0, mv1, mv2, mv3};
  float ls = 0.f;
  shortx4 pf[4];
#pragma unroll
  for (int ct = 0; ct < 4; ++ct) {
    float pr[4];
#pragma unroll
    for (int r = 0; r < 4; ++r)
      pr[r] = (mv[ct][r] + 1e-6f) * __builtin_amdgcn_exp2f(s[ct][r]);
    if (TAIL) {
      const int kk = k0 + ct * 16 + quad * 4;
#pragma unroll
      for (int r = 0; r < 4; ++r) if (kk + r >= S_LEN) pr[r] = 0.f;
    }
    ls += (pr[0] + pr[1]) + (pr[2] + pr[3]);
    union { bf16x4 b4; shortx4 s4; } u;
    u.b4[0]=(__bf16)pr[0]; u.b4[1]=(__bf16)pr[1]; u.b4[2]=(__bf16)pr[2]; u.b4[3]=(__bf16)pr[3];
    pf[ct] = u.s4;
  }
  l_run += ls;
#pragma unroll
  for (int ct = 0; ct < 4; ++ct) {
    o0 = __builtin_amdgcn_mfma_f32_16x16x16bf16_1k(v0[ct], pf[ct], o0, 0, 0, 0);
    o1 = __builtin_amdgcn_mfma_f32_16x16x16bf16_1k(v1[ct], pf[ct], o1, 0, 0, 0);
  }
}

__global__ __launch_bounds__(256, 3) void k_flash(
    const unsigned short* __restrict__ qws,
    const unsigned short* __restrict__ kws,
    const unsigned short* __restrict__ vfrag,
    const float* __restrict__ mask,
    const unsigned short* __restrict__ lepe,
    unsigned short* __restrict__ attn)
{
  // Per-wave 8KB region: 2 x 4KB mask dbuf during the loop; first 576 floats
  // reused as reduction scratch AFTER the wave's loop.
  __shared__ __align__(16) float smem[4][2048];
  const int lane = threadIdx.x & 63;
  const int wid  = threadIdx.x >> 6;
  const int c    = lane & 15, quad = lane >> 4;
  const int u    = blockIdx.x;               // 0..3199
  const int xcd  = u & 7;
  const int slot = u >> 3;                   // 0..399
  const int h    = slot & 7;
  const int p    = (slot >> 3) * 8 + xcd;    // 0..399 = b*200 + strip
  const int b    = p / 200;
  const int strip = p - b * 200;
  const int qrow = strip * 16 + c;
  const size_t bh = (size_t)(b * HEADS + h);

  const bf16x8 qf = *(const bf16x8*)(qws + (bh * SP + qrow) * HD + quad * 8);
  const unsigned short* kb = kws + bh * SP * HD;
  const unsigned short* vb = vfrag + bh * (size_t)(50 * 2048);
  float* mt = &smem[wid][0];

  // Mask LDS read addresses (byte offsets in LDS space), buf0 and buf1.
  unsigned au[4], ad[4];
  {
    const unsigned base = (unsigned)(size_t)(LDS_AS void*)&smem[wid][0];
#pragma unroll
    for (int ct = 0; ct < 4; ++ct) {
      au[ct] = base + (unsigned)((c * 64 + (((ct * 4 + quad) ^ c) & 15) * 4) * 4);
      ad[ct] = au[ct] + 4096u;
    }
  }

  // Staging source precompute: instr i covers q-rows i*4..i*4+3; lane supplies
  // (row = i*4 + lane>>4, G' = lane&15), source granule G = G' ^ row.
  const float* msrc[4];
  int goff4[4];
#pragma unroll
  for (int i = 0; i < 4; ++i) {
    const int rq = i * 4 + (lane >> 4);
    int mr = strip * 16 + rq; if (mr >= S_LEN) mr = S_LEN - 1;
    msrc[i] = mask + ((size_t)b * S_LEN + mr) * S_LEN;
    goff4[i] = ((lane & 15) ^ rq) * 4;
  }

  float l_run = 0.f;
  floatx4 o0 = (floatx4){0.f,0.f,0.f,0.f};
  floatx4 o1 = (floatx4){0.f,0.f,0.f,0.f};

  // tiles j=0..11: t = wid*12 + j; extra tile 48+wid for waves 0/1 (49 = tail).
  const int tbase = wid * 12;
  bf16x8 kfA[4], kfB[4];
  shortx4 v0A[4], v1A[4], v0B[4], v1B[4];

  stage_mask(msrc, goff4, tbase * 64, mt);                      // buf0
  load_reg(kb, vb, tbase, c, quad, lane, kfA, v0A, v1A);

#pragma unroll 1
  for (int itp = 0; itp < 6; ++itp) {
    const int j0 = 2 * itp;
    // even phase: prefetch tile j0+1 into B/buf1, compute A(tile j0) from buf0
    load_reg(kb, vb, tbase + j0 + 1, c, quad, lane, kfB, v0B, v1B);
    stage_mask(msrc, goff4, (tbase + j0 + 1) * 64, mt + 1024);
    FENCE16();
    proc_reg<false>(0, kfA, v0A, v1A, au, quad, qf, o0, o1, l_run);
    // odd phase: prefetch next into A/buf0, compute B(tile j0+1) from buf1
    if (itp < 5) {
      load_reg(kb, vb, tbase + j0 + 2, c, quad, lane, kfA, v0A, v1A);
      stage_mask(msrc, goff4, (tbase + j0 + 2) * 64, mt);
      FENCE16();
    } else if (wid == 0) {
      load_reg(kb, vb, 48, c, quad, lane, kfA, v0A, v1A);
      stage_mask(msrc, goff4, 48 * 64, mt);
      FENCE16();
    } else if (wid == 1) {
      load_reg(kb, vb, 49, c, quad, lane, kfA, v0A, v1A);
      stage_mask_tail(msrc, goff4, 49 * 64, mt);
      FENCE16();
    } else {
      FENCE0();
    }
    proc_reg<false>(0, kfB, v0B, v1B, ad, quad, qf, o0, o1, l_run);
  }
  if (wid == 0) {
    FENCE0();
    proc_reg<false>(0, kfA, v0A, v1A, au, quad, qf, o0, o1, l_run);
  } else if (wid == 1) {
    FENCE0();
    proc_reg<true>(49 * 64, kfA, v0A, v1A, au, quad, qf, o0, o1, l_run);
  }

  // ---- cross-wave reduction (smem reused: each wave writes only its region) ----
#pragma unroll
  for (int r = 0; r < 4; ++r) {
    smem[wid][lane * 9 + r]     = o0[r];
    smem[wid][lane * 9 + 4 + r] = o1[r];
  }
  smem[wid][lane * 9 + 8] = l_run;
  __syncthreads();

  if (wid == 0) {
#pragma unroll
    for (int w = 1; w < 4; ++w) {
#pragma unroll
      for (int r = 0; r < 4; ++r) {
        o0[r] += smem[w][lane * 9 + r];
        o1[r] += smem[w][lane * 9 + 4 + r];
      }
      l_run += smem[w][lane * 9 + 8];
    }
    l_run += __shfl_xor(l_run, 16);
    l_run += __shfl_xor(l_run, 32);
    const float rl = 1.f / l_run;

    if (qrow < S_LEN) {
      const size_t obase = ((size_t)b * S_LEN + qrow) * 256 + h * 32;
      const size_t lbase = (qrow >= 8) ? (((size_t)b * NPIX + (qrow - 8)) * 256 + h * 32) : 0;
#pragma unroll
      for (int mt2 = 0; mt2 < 2; ++mt2) {
        floatx4 ov = mt2 ? o1 : o0;
#pragma unroll
        for (int r = 0; r < 4; ++r) {
          const int d = mt2 * 16 + quad * 4 + r;
          float val = ov[r] * rl;
          if (qrow >= 8) val += bf2f(lepe[lbase + d]);
          attn[obase + d] = f2bf(val);
        }
      }
    }
  }
}

// ---------------- K4: output projection (attn bf16, wo/bo f32 -> f32 out) ----------------
__global__ __launch_bounds__(256) void k_oproj(
    const unsigned short* __restrict__ attn,
    const float* __restrict__ wop,
    const float* __restrict__ bop,
    float* __restrict__ out)
{
  const int lane = threadIdx.x & 63;
  const int wid  = threadIdx.x >> 6;
  const int c = lane & 15, quad = lane >> 4;
  const int row0 = blockIdx.x * 64 + wid * 16;
  const int col0 = blockIdx.y * 64;

  int arow = row0 + c; if (arow >= MROWS) arow = 0;
  const unsigned short* ap = attn + (size_t)arow * 256 + quad * 8;
  const float* bp = wop + (size_t)(col0 + c) * 256 + quad * 8;

  floatx4 acc[4];
#pragma unroll
  for (int ct = 0; ct < 4; ++ct) acc[ct] = (floatx4){0.f,0.f,0.f,0.f};
#pragma unroll
  for (int ks = 0; ks < 8; ++ks) {
    bf16x8 af = *(const bf16x8*)(ap + ks * 32);
#pragma unroll
    for (int ct = 0; ct < 4; ++ct) {
      bf16x8 bf = ldcvt8(bp + (size_t)ct * 16 * 256 + ks * 32);
      acc[ct] = __builtin_amdgcn_mfma_f32_16x16x32_bf16(af, bf, acc[ct], 0, 0, 0);
    }
  }
#pragma unroll
  for (int ct = 0; ct < 4; ++ct) {
    const int col = col0 + ct * 16 + c;
    const float bias = bop[col];
#pragma unroll
    for (int r = 0; r < 4; ++r) {
      const int row = row0 + quad * 4 + r;
      if (row >= MROWS) continue;
      out[(size_t)row * 256 + col] = acc[ct][r] + bias;
    }
  }
}

// ---------------- workspace layout (bytes), total 16,261,120 ----------------
#define QW_OFF 0u                        // 2*8*3200*32*2 = 3,276,800
#define KW_OFF 3276800u
#define VF_OFF 6553600u                  // vfrag, 3,276,800
#define LE_OFF 9830400u                  // w3b (384KB) until k_lepe overwrites with lepe
#define AT_OFF 13041664u                 // 6288*256*2    = 3,219,456

extern "C" void kernel_launch(void* const* d_in, const int* in_sizes, int n_in,
                              void* d_out, int out_size, void* d_ws, size_t ws_size,
                              hipStream_t stream) {
  const float* x    = (const float*)d_in[0];
  const float* mask = (const float*)d_in[1];
  const float* wq   = (const float*)d_in[2];
  const float* bq   = (const float*)d_in[3];
  const float* wk   = (const float*)d_in[4];
  const float* bk   = (const float*)d_in[5];
  const float* wv   = (const float*)d_in[6];
  const float* bv   = (const float*)d_in[7];
  const float* lw   = (const float*)d_in[8];
  const float* lb   = (const float*)d_in[9];
  const float* wo   = (const float*)d_in[10];
  const float* bo   = (const float*)d_in[11];

  char* ws = (char*)d_ws;
  unsigned short* qws = (unsigned short*)(ws + QW_OFF);
  unsigned short* kws = (unsigned short*)(ws + KW_OFF);
  unsigned short* vfr = (unsigned short*)(ws + VF_OFF);
  unsigned short* w3b = (unsigned short*)(ws + LE_OFF);   // dead before k_lepe
  unsigned short* lpe = (unsigned short*)(ws + LE_OFF);
  unsigned short* atb = (unsigned short*)(ws + AT_OFF);
  unsigned short* vst = (unsigned short*)d_out;             // low 3.22MB of d_out
  unsigned short* xb  = (unsigned short*)d_out + 1609728;   // high 3.22MB of d_out
  float*          outf = (float*)d_out;

  k_cvt<<<882, 256, 0, stream>>>(x, wq, wk, wv, xb, w3b);
  k_qkv<<<dim3(100, 12), 256, 0, stream>>>(xb, w3b, bq, bk, bv, qws, kws, vfr, vst);
  k_lepe<<<784, 256, 0, stream>>>(vst, lw, lb, lpe);
  k_flash<<<3200, 256, 0, stream>>>(qws, kws, vfr, mask, lpe, atb);
  k_oproj<<<dim3(99, 4), 256, 0, stream>>>(atb, wo, bo, outf);
}

// Round 3
// 311.832 us; speedup vs baseline: 1.2020x; 1.2020x over previous
//
#include <hip/hip_runtime.h>

// MaskAttention: B=2,S=3144,C=256,H=8,HD=32, mask-softmax attention with vh=kh,
// LePE 5x5 depthwise conv on v[:,8:], output projection.
// I/O: ALL float32. Internal: bf16 MFMA, f32 accum.
//
// softmax(qk + log(m+eps)) == normalize((m+eps)*exp(qk)); |qk| is tiny, so fixed
// shift M=0 -> no online max; k-range partials additive => split-K.
//
// R3 changes vs R2 (201us k_flash, spill catastrophe):
//  - k_flash reverted to the R1 structure (loads INSIDE proc_tile, LDS mask
//    dbuf via global_load_lds + counted vmcnt(4), compiler-visible LDS reads).
//    R2's explicit register dbuf + launch_bounds(256,3) + asm ds_read made the
//    allocator demote tile buffers to scratch (WRITE_SIZE 3.6MB -> 185MB).
//  - 8 waves / 512 threads per block: split-K depth 12-13 -> 6-7 tiles/wave,
//    resident waves/CU ~10 -> 16 (LDS 64KB, 2 blocks/CU). Latency-bound kernel
//    gets 2x issue parallelism.
//  - keeps R2's wins: k_cvt bf16 prepass, bf16 k_qkv, kws pre-scaled by
//    SCALE*log2e so softmax is a raw v_exp_f32 (exp2), vfrag unchanged.

#define S_LEN 3144
#define SP    3200            // S padded to 64 (50 k-tiles; 0..48 fully valid)
#define HEADS 8
#define HD    32
#define BATCH 2
#define MROWS (BATCH*S_LEN)   // 6288
#define NPIX  3136            // 56*56
#define SCALE_F 0.17677669529663687f   // 32^-0.5
#define KQ_SC   0.25504472665352026f   // SCALE_F * log2(e)

typedef __bf16 bf16x8  __attribute__((ext_vector_type(8)));
typedef __bf16 bf16x4  __attribute__((ext_vector_type(4)));
typedef float  floatx4 __attribute__((ext_vector_type(4)));
typedef short  shortx4 __attribute__((ext_vector_type(4)));

static __device__ __forceinline__ float bf2f(unsigned int h) {
  union { unsigned int u; float f; } v; v.u = h << 16; return v.f;
}
static __device__ __forceinline__ unsigned short f2bf(float f) {
  union { __bf16 b; unsigned short u; } v; v.b = (__bf16)f; return v.u;
}
static __device__ __forceinline__ bf16x8 ldcvt8(const float* __restrict__ p) {
  float4 a = *(const float4*)p;
  float4 b = *(const float4*)(p + 4);
  bf16x8 r;
  r[0]=(__bf16)a.x; r[1]=(__bf16)a.y; r[2]=(__bf16)a.z; r[3]=(__bf16)a.w;
  r[4]=(__bf16)b.x; r[5]=(__bf16)b.y; r[6]=(__bf16)b.z; r[7]=(__bf16)b.w;
  return r;
}

#define GLOBAL_AS __attribute__((address_space(1)))
#define LDS_AS    __attribute__((address_space(3)))
static __device__ __forceinline__ void gload_lds16(const void* g, void* l) {
  __builtin_amdgcn_global_load_lds((const GLOBAL_AS void*)g, (LDS_AS void*)l, 16, 0, 0);
}

#define FENCE4() asm volatile("s_waitcnt vmcnt(4)" ::: "memory")
#define FENCE0() asm volatile("s_waitcnt vmcnt(0)" ::: "memory")

// ---------------- K0: one-time f32 -> bf16 conversion (x, wq, wk, wv) ----------------
__global__ __launch_bounds__(256) void k_cvt(
    const float* __restrict__ x, const float* __restrict__ wq,
    const float* __restrict__ wk, const float* __restrict__ wv,
    unsigned short* __restrict__ xb, unsigned short* __restrict__ w3b)
{
  const int i = blockIdx.x * 256 + threadIdx.x;   // unit of 8 floats
  const int NX = MROWS * 32;                      // 201216
  const int NW = 8192;                            // 65536/8
  const float* src;
  unsigned short* dst;
  if (i < NX) { src = x + (size_t)i * 8; dst = xb + (size_t)i * 8; }
  else {
    const int j = i - NX;
    if (j >= 3 * NW) return;
    src = (j < NW) ? wq + (size_t)j * 8
        : (j < 2 * NW) ? wk + (size_t)(j - NW) * 8
                       : wv + (size_t)(j - 2 * NW) * 8;
    dst = w3b + (size_t)j * 8;
  }
  bf16x8 v = ldcvt8(src);
  *(bf16x8*)dst = v;
}

// ---------------- K1: fused q/k/v projection (bf16 in -> bf16 out) ----------------
// Grid (100, 12): blockIdx.x = bsel*50 + stile. Pad rows (s>=S_LEN) store 0.
__global__ __launch_bounds__(256) void k_qkv(
    const unsigned short* __restrict__ xb, const unsigned short* __restrict__ w3b,
    const float* __restrict__ bqp, const float* __restrict__ bkp,
    const float* __restrict__ bvp,
    unsigned short* __restrict__ qws, unsigned short* __restrict__ kws,
    unsigned short* __restrict__ vfrag, unsigned short* __restrict__ vstage)
{
  __shared__ unsigned short lds_t[64 * 65];   // transpose staging (k blocks only)
  const int lane = threadIdx.x & 63;
  const int wid  = threadIdx.x >> 6;
  const int c    = lane & 15, quad = lane >> 4;
  const int bsel  = blockIdx.x / 50;
  const int stile = blockIdx.x % 50;
  const int srow0 = stile * 64;
  const int ncol = blockIdx.y * 64;           // 0..767
  const int wsel = ncol >> 8;
  const int col0 = ncol & 255;

  const float* bptr = (wsel == 0) ? bqp : (wsel == 1) ? bkp : bvp;

  const int srow = srow0 + wid * 16 + c;
  const int arow = bsel * S_LEN + ((srow < S_LEN) ? srow : 0);  // clamp pad rows
  const unsigned short* ap = xb  + (size_t)arow * 256 + quad * 8;
  const unsigned short* bp = w3b + (size_t)(ncol + c) * 256 + quad * 8;

  floatx4 acc[4];
#pragma unroll
  for (int ct = 0; ct < 4; ++ct) acc[ct] = (floatx4){0.f, 0.f, 0.f, 0.f};

#pragma unroll
  for (int ks = 0; ks < 8; ++ks) {
    bf16x8 af = *(const bf16x8*)(ap + ks * 32);
#pragma unroll
    for (int ct = 0; ct < 4; ++ct) {
      bf16x8 bf = *(const bf16x8*)(bp + (size_t)ct * 16 * 256 + ks * 32);
      acc[ct] = __builtin_amdgcn_mfma_f32_16x16x32_bf16(af, bf, acc[ct], 0, 0, 0);
    }
  }

#pragma unroll
  for (int ct = 0; ct < 4; ++ct) {
    const int col = col0 + ct * 16 + c;
    const float bias = bptr[col];
#pragma unroll
    for (int r = 0; r < 4; ++r) {
      const int s = srow0 + wid * 16 + quad * 4 + r;   // 0..3199 within batch
      const int valid = (s < S_LEN);
      const float v = acc[ct][r] + bias;
      if (wsel == 0) {
        qws[(((size_t)(bsel * HEADS + (col >> 5))) * SP + s) * HD + (col & 31)] =
            valid ? f2bf(v) : (unsigned short)0;
      } else if (wsel == 1) {
        // QK-side copy carries log2e; V-side copy (lds_t->vfrag) does NOT.
        kws[(((size_t)(bsel * HEADS + (col >> 5))) * SP + s) * HD + (col & 31)] =
            valid ? f2bf(v * KQ_SC) : (unsigned short)0;
        lds_t[(ct * 16 + c) * 65 + (wid * 16 + quad * 4 + r)] =
            valid ? f2bf(v * SCALE_F) : (unsigned short)0;
      } else {
        if (valid) vstage[(size_t)(bsel * S_LEN + s) * 256 + col] = f2bf(v);
      }
    }
  }

  if (wsel == 1) {
    // vfrag: PV A-operand fragments in exact MFMA lane order.
    __syncthreads();
    const int tid = threadIdx.x;
#pragma unroll
    for (int j = 0; j < 4; ++j) {
      const int grp  = j * 4 + (tid >> 6);   // 0..15, wave-uniform
      const int l    = tid & 63;
      const int ct2  = grp & 3;
      const int half = (grp >> 2) & 1;
      const int hsel = grp >> 3;
      const int cc = l & 15, qq = l >> 4;
      const int cl = hsel * 32 + half * 16 + cc;
      const int rb = ct2 * 16 + qq * 4;
      union { shortx4 s4; unsigned short u[4]; } pk;
#pragma unroll
      for (int e = 0; e < 4; ++e) pk.u[e] = lds_t[cl * 65 + rb + e];
      const int hglob = (col0 >> 5) + hsel;
      const size_t off =
          ((((size_t)(bsel * HEADS + hglob) * 50 + stile) * 4 + ct2) * 2 + half) * 64 + l;
      *(shortx4*)(vfrag + off * 4) = pk.s4;
    }
  }
}

// ---------------- K2: LePE 5x5 depthwise conv on v[:,8:] ----------------
__global__ __launch_bounds__(256) void k_lepe(const unsigned short* __restrict__ vws,
                                              const float* __restrict__ cw,
                                              const float* __restrict__ cb,
                                              unsigned short* __restrict__ lepe)
{
  int idx = blockIdx.x * 256 + threadIdx.x;
  if (idx >= BATCH * NPIX * 32) return;
  const int cg = idx & 31;
  const int p  = (idx >> 5) % NPIX;
  const int b  = idx / (NPIX * 32);
  const int y  = p / 56, xx = p - y * 56;

  float acc[8];
  {
    float4 b0 = *(const float4*)(cb + cg * 8);
    float4 b1 = *(const float4*)(cb + cg * 8 + 4);
    acc[0]=b0.x; acc[1]=b0.y; acc[2]=b0.z; acc[3]=b0.w;
    acc[4]=b1.x; acc[5]=b1.y; acc[6]=b1.z; acc[7]=b1.w;
  }
#pragma unroll
  for (int dy = -2; dy <= 2; ++dy) {
    const int yy = y + dy;
    if ((unsigned)yy >= 56u) continue;
#pragma unroll
    for (int dx = -2; dx <= 2; ++dx) {
      const int xs = xx + dx;
      if ((unsigned)xs >= 56u) continue;
      uint4 vv = *(const uint4*)(vws + (size_t)(b * S_LEN + 8 + yy * 56 + xs) * 256 + cg * 8);
      const float* wp = cw + (size_t)((dy + 2) * 5 + (dx + 2)) * 256 + cg * 8;
      float4 w0 = *(const float4*)wp;
      float4 w1 = *(const float4*)(wp + 4);
      unsigned int va[4] = {vv.x, vv.y, vv.z, vv.w};
      acc[0] += bf2f(va[0] & 0xFFFFu) * w0.x;  acc[1] += bf2f(va[0] >> 16) * w0.y;
      acc[2] += bf2f(va[1] & 0xFFFFu) * w0.z;  acc[3] += bf2f(va[1] >> 16) * w0.w;
      acc[4] += bf2f(va[2] & 0xFFFFu) * w1.x;  acc[5] += bf2f(va[2] >> 16) * w1.y;
      acc[6] += bf2f(va[3] & 0xFFFFu) * w1.z;  acc[7] += bf2f(va[3] >> 16) * w1.w;
    }
  }
  unsigned int o[4];
#pragma unroll
  for (int j = 0; j < 4; ++j)
    o[j] = (unsigned int)f2bf(acc[2*j]) | ((unsigned int)f2bf(acc[2*j+1]) << 16);
  *((uint4*)(lepe + (size_t)(b * NPIX + p) * 256 + cg * 8)) = make_uint4(o[0], o[1], o[2], o[3]);
}

// ---------------- K3: flash attention, split-K (8 waves) + XCD-aware swizzle ----------------
// Mask staged to per-wave LDS dbuf via global_load_lds (structural prefetch),
// counted vmcnt(4) fence; k/v loads left inside proc_tile for the compiler to
// schedule (R1-proven: VGPR 64, zero scratch).
template<bool TAIL>
static __device__ __forceinline__ void proc_tile(
    int t, const unsigned short* __restrict__ kb,
    const unsigned short* __restrict__ vb,
    const float* __restrict__ mb,
    int c, int quad, int lane, const bf16x8 qf,
    floatx4& o0, floatx4& o1, float& l_run)
{
  const int k0 = t * 64;
  bf16x8 kf[4]; shortx4 v0[4], v1[4];
  const unsigned short* tb = vb + (size_t)t * 2048;
#pragma unroll
  for (int ct = 0; ct < 4; ++ct) {
    kf[ct] = *(const bf16x8*)(kb + (size_t)(k0 + ct * 16 + c) * HD + quad * 8);
    v0[ct] = *(const shortx4*)(tb + (ct * 2 + 0) * 256 + lane * 4);
    v1[ct] = *(const shortx4*)(tb + (ct * 2 + 1) * 256 + lane * 4);
  }
  floatx4 s[4];
#pragma unroll
  for (int ct = 0; ct < 4; ++ct)
    s[ct] = __builtin_amdgcn_mfma_f32_16x16x32_bf16(kf[ct], qf,
               (floatx4){0.f,0.f,0.f,0.f}, 0, 0, 0);
  float ls = 0.f;
  shortx4 pf[4];
#pragma unroll
  for (int ct = 0; ct < 4; ++ct) {
    const float4 mv = *(const float4*)(mb + c * 64 + (((ct * 4 + quad) ^ c) * 4));
    float pr[4];
    pr[0] = (mv.x + 1e-6f) * __builtin_amdgcn_exp2f(s[ct][0]);
    pr[1] = (mv.y + 1e-6f) * __builtin_amdgcn_exp2f(s[ct][1]);
    pr[2] = (mv.z + 1e-6f) * __builtin_amdgcn_exp2f(s[ct][2]);
    pr[3] = (mv.w + 1e-6f) * __builtin_amdgcn_exp2f(s[ct][3]);
    if (TAIL) {
      const int kk = k0 + ct * 16 + quad * 4;
#pragma unroll
      for (int r = 0; r < 4; ++r) if (kk + r >= S_LEN) pr[r] = 0.f;
    }
    ls += (pr[0] + pr[1]) + (pr[2] + pr[3]);
    union { bf16x4 b4; shortx4 s4; } u;
    u.b4[0]=(__bf16)pr[0]; u.b4[1]=(__bf16)pr[1]; u.b4[2]=(__bf16)pr[2]; u.b4[3]=(__bf16)pr[3];
    pf[ct] = u.s4;
  }
  l_run += ls;
#pragma unroll
  for (int ct = 0; ct < 4; ++ct) {
    o0 = __builtin_amdgcn_mfma_f32_16x16x16bf16_1k(v0[ct], pf[ct], o0, 0, 0, 0);
    o1 = __builtin_amdgcn_mfma_f32_16x16x16bf16_1k(v1[ct], pf[ct], o1, 0, 0, 0);
  }
}

static __device__ __forceinline__ void stage_mask(
    const float* const (&msrc)[4], const int (&goff4)[4], int k0, float* dst)
{
#pragma unroll
  for (int i = 0; i < 4; ++i)
    gload_lds16(msrc[i] + (k0 + goff4[i]), dst + i * 256);
}

static __device__ __forceinline__ void stage_mask_tail(
    const float* const (&msrc)[4], const int (&goff4)[4], int k0, float* dst)
{
#pragma unroll
  for (int i = 0; i < 4; ++i) {
    int kk = k0 + goff4[i];
    if (kk > S_LEN - 4) kk = S_LEN - 4;   // stay in-bounds; zeroed in softmax
    gload_lds16(msrc[i] + kk, dst + i * 256);
  }
}

__global__ __launch_bounds__(512) void k_flash(
    const unsigned short* __restrict__ qws,
    const unsigned short* __restrict__ kws,
    const unsigned short* __restrict__ vfrag,
    const float* __restrict__ mask,
    const unsigned short* __restrict__ lepe,
    unsigned short* __restrict__ attn)
{
  // Per-wave 8KB region: 2 x 4KB mask dbuf during the loop; first 576 floats
  // reused as reduction scratch AFTER the wave's loop.
  __shared__ __align__(16) float smem[8][2048];
  const int lane = threadIdx.x & 63;
  const int wid  = threadIdx.x >> 6;          // 0..7
  const int c    = lane & 15, quad = lane >> 4;
  const int u    = blockIdx.x;               // 0..3199
  const int xcd  = u & 7;
  const int slot = u >> 3;                   // 0..399
  const int h    = slot & 7;
  const int p    = (slot >> 3) * 8 + xcd;    // 0..399 = b*200 + strip
  const int b    = p / 200;
  const int strip = p - b * 200;
  const int qrow = strip * 16 + c;
  const size_t bh = (size_t)(b * HEADS + h);

  const bf16x8 qf = *(const bf16x8*)(qws + (bh * SP + qrow) * HD + quad * 8);
  const unsigned short* kb = kws + bh * SP * HD;
  const unsigned short* vb = vfrag + bh * (size_t)(50 * 2048);
  float* mt = &smem[wid][0];

  // Staging source precompute: instr i covers q-rows i*4..i*4+3; lane supplies
  // (row = i*4 + lane>>4, G' = lane&15), source granule G = G' ^ row.
  const float* msrc[4];
  int goff4[4];
#pragma unroll
  for (int i = 0; i < 4; ++i) {
    const int rq = i * 4 + (lane >> 4);
    int mr = strip * 16 + rq; if (mr >= S_LEN) mr = S_LEN - 1;
    msrc[i] = mask + ((size_t)b * S_LEN + mr) * S_LEN;
    goff4[i] = ((lane & 15) ^ rq) * 4;
  }

  float l_run = 0.f;
  floatx4 o0 = (floatx4){0.f,0.f,0.f,0.f};
  floatx4 o1 = (floatx4){0.f,0.f,0.f,0.f};

  // tiles: wave w -> t = w*6 .. w*6+5 (48 tiles); leftovers 48 -> wave0,
  // 49 (tail) -> wave1.
  const int tbase = wid * 6;
  const int nt = (wid < 2) ? 7 : 6;

  stage_mask(msrc, goff4, tbase * 64, mt);    // prologue: tile tbase -> buf0

  for (int it = 0; it < nt; ++it) {
    const int t = (it < 6) ? tbase + it : 48 + wid;
    if (it + 1 < nt) {
      const int tn = (it + 1 < 6) ? tbase + it + 1 : 48 + wid;
      float* dst = mt + ((it + 1) & 1) * 1024;
      if (tn == 49) stage_mask_tail(msrc, goff4, 49 * 64, dst);
      else          stage_mask(msrc, goff4, tn * 64, dst);
      FENCE4();   // retire THIS tile's 4 staging loads; keep next 4 in flight
    } else {
      FENCE0();
    }
    const float* mb = mt + (it & 1) * 1024;
    if (wid == 1 && it == 6)
      proc_tile<true >(t, kb, vb, mb, c, quad, lane, qf, o0, o1, l_run);
    else
      proc_tile<false>(t, kb, vb, mb, c, quad, lane, qf, o0, o1, l_run);
  }

  // ---- cross-wave reduction (smem reused: each wave writes only its region) ----
#pragma unroll
  for (int r = 0; r < 4; ++r) {
    smem[wid][lane * 9 + r]     = o0[r];
    smem[wid][lane * 9 + 4 + r] = o1[r];
  }
  smem[wid][lane * 9 + 8] = l_run;
  __syncthreads();

  if (wid == 0) {
#pragma unroll
    for (int w = 1; w < 8; ++w) {
#pragma unroll
      for (int r = 0; r < 4; ++r) {
        o0[r] += smem[w][lane * 9 + r];
        o1[r] += smem[w][lane * 9 + 4 + r];
      }
      l_run += smem[w][lane * 9 + 8];
    }
    l_run += __shfl_xor(l_run, 16);
    l_run += __shfl_xor(l_run, 32);
    const float rl = 1.f / l_run;

    if (qrow < S_LEN) {
      const size_t obase = ((size_t)b * S_LEN + qrow) * 256 + h * 32;
      const size_t lbase = (qrow >= 8) ? (((size_t)b * NPIX + (qrow - 8)) * 256 + h * 32) : 0;
#pragma unroll
      for (int mt2 = 0; mt2 < 2; ++mt2) {
        floatx4 ov = mt2 ? o1 : o0;
#pragma unroll
        for (int r = 0; r < 4; ++r) {
          const int d = mt2 * 16 + quad * 4 + r;
          float val = ov[r] * rl;
          if (qrow >= 8) val += bf2f(lepe[lbase + d]);
          attn[obase + d] = f2bf(val);
        }
      }
    }
  }
}

// ---------------- K4: output projection (attn bf16, wo/bo f32 -> f32 out) ----------------
__global__ __launch_bounds__(256) void k_oproj(
    const unsigned short* __restrict__ attn,
    const float* __restrict__ wop,
    const float* __restrict__ bop,
    float* __restrict__ out)
{
  const int lane = threadIdx.x & 63;
  const int wid  = threadIdx.x >> 6;
  const int c = lane & 15, quad = lane >> 4;
  const int row0 = blockIdx.x * 64 + wid * 16;
  const int col0 = blockIdx.y * 64;

  int arow = row0 + c; if (arow >= MROWS) arow = 0;
  const unsigned short* ap = attn + (size_t)arow * 256 + quad * 8;
  const float* bp = wop + (size_t)(col0 + c) * 256 + quad * 8;

  floatx4 acc[4];
#pragma unroll
  for (int ct = 0; ct < 4; ++ct) acc[ct] = (floatx4){0.f,0.f,0.f,0.f};
#pragma unroll
  for (int ks = 0; ks < 8; ++ks) {
    bf16x8 af = *(const bf16x8*)(ap + ks * 32);
#pragma unroll
    for (int ct = 0; ct < 4; ++ct) {
      bf16x8 bf = ldcvt8(bp + (size_t)ct * 16 * 256 + ks * 32);
      acc[ct] = __builtin_amdgcn_mfma_f32_16x16x32_bf16(af, bf, acc[ct], 0, 0, 0);
    }
  }
#pragma unroll
  for (int ct = 0; ct < 4; ++ct) {
    const int col = col0 + ct * 16 + c;
    const float bias = bop[col];
#pragma unroll
    for (int r = 0; r < 4; ++r) {
      const int row = row0 + quad * 4 + r;
      if (row >= MROWS) continue;
      out[(size_t)row * 256 + col] = acc[ct][r] + bias;
    }
  }
}

// ---------------- workspace layout (bytes), total 16,261,120 ----------------
#define QW_OFF 0u                        // 2*8*3200*32*2 = 3,276,800
#define KW_OFF 3276800u
#define VF_OFF 6553600u                  // vfrag, 3,276,800
#define LE_OFF 9830400u                  // w3b (384KB) until k_lepe overwrites with lepe
#define AT_OFF 13041664u                 // 6288*256*2    = 3,219,456

extern "C" void kernel_launch(void* const* d_in, const int* in_sizes, int n_in,
                              void* d_out, int out_size, void* d_ws, size_t ws_size,
                              hipStream_t stream) {
  const float* x    = (const float*)d_in[0];
  const float* mask = (const float*)d_in[1];
  const float* wq   = (const float*)d_in[2];
  const float* bq   = (const float*)d_in[3];
  const float* wk   = (const float*)d_in[4];
  const float* bk   = (const float*)d_in[5];
  const float* wv   = (const float*)d_in[6];
  const float* bv   = (const float*)d_in[7];
  const float* lw   = (const float*)d_in[8];
  const float* lb   = (const float*)d_in[9];
  const float* wo   = (const float*)d_in[10];
  const float* bo   = (const float*)d_in[11];

  char* ws = (char*)d_ws;
  unsigned short* qws = (unsigned short*)(ws + QW_OFF);
  unsigned short* kws = (unsigned short*)(ws + KW_OFF);
  unsigned short* vfr = (unsigned short*)(ws + VF_OFF);
  unsigned short* w3b = (unsigned short*)(ws + LE_OFF);   // dead before k_lepe
  unsigned short* lpe = (unsigned short*)(ws + LE_OFF);
  unsigned short* atb = (unsigned short*)(ws + AT_OFF);
  unsigned short* vst = (unsigned short*)d_out;             // low 3.22MB of d_out
  unsigned short* xb  = (unsigned short*)d_out + 1609728;   // high 3.22MB of d_out
  float*          outf = (float*)d_out;

  k_cvt<<<882, 256, 0, stream>>>(x, wq, wk, wv, xb, w3b);
  k_qkv<<<dim3(100, 12), 256, 0, stream>>>(xb, w3b, bq, bk, bv, qws, kws, vfr, vst);
  k_lepe<<<784, 256, 0, stream>>>(vst, lw, lb, lpe);
  k_flash<<<3200, 512, 0, stream>>>(qws, kws, vfr, mask, lpe, atb);
  k_oproj<<<dim3(99, 4), 256, 0, stream>>>(atb, wo, bo, outf);
}